// Round 7
// baseline (243.208 us; speedup 1.0000x reference)
//
#include <hip/hip_runtime.h>
#include <stdint.h>

#define HASH_BUCKETS 1000
#define EMB_DIM 16
#define HDIM 32
#define G4 128   // 4*HDIM
#define TSTEPS 512
#define BATCH 4096

typedef short v8s __attribute__((ext_vector_type(8)));   // 8 bf16 (4 VGPRs)
typedef float v4f __attribute__((ext_vector_type(4)));   // MFMA acc
typedef float v2f __attribute__((ext_vector_type(2)));   // packed f32 pair

__device__ __forceinline__ float frcp(float x) {
    float r; asm("v_rcp_f32 %0, %1" : "=v"(r) : "v"(x)); return r;
}
__device__ __forceinline__ float fexp2(float x) {
    float r; asm("v_exp_f32 %0, %1" : "=v"(r) : "v"(x)); return r;
}
// packed f32->bf16 (RNE): dst.lo16 = bf16(a), dst.hi16 = bf16(b)
__device__ __forceinline__ uint32_t cvtpk_bf16(float a, float b) {
    uint32_t r; asm("v_cvt_pk_bf16_f32 %0, %1, %2" : "=v"(r) : "v"(a), "v"(b)); return r;
}
// f32 -> bf16 (RNE), bits in low 16 (A-build only, once per launch)
__device__ __forceinline__ uint32_t bf16rne(float x) {
    uint32_t u = __float_as_uint(x);
    return (u + 0x7FFFu + ((u >> 16) & 1u)) >> 16;
}

// ---------------------------------------------------------------------------
// Kernel 1 (unchanged): embedding folded through input projection, gate
// exp2-scaling folded in: i/f/o rows x (-log2 e), c-row x (+2 log2 e).
// P2[bucket][h][g] = s_g * sum_e emb[bucket][e] * kernel[e][g*32 + h]
// ---------------------------------------------------------------------------
__global__ void precompute_P2_kernel(const float* __restrict__ emb,
                                     const float* __restrict__ kern,
                                     float* __restrict__ P2) {
    int idx = blockIdx.x * blockDim.x + threadIdx.x;
    if (idx >= HASH_BUCKETS * G4) return;
    int row = idx >> 7;
    int c2  = idx & 127;
    int h = c2 >> 2;
    int g = c2 & 3;
    float acc = 0.f;
#pragma unroll
    for (int e = 0; e < EMB_DIM; ++e)
        acc = fmaf(emb[row * EMB_DIM + e], kern[e * G4 + g * 32 + h], acc);
    float sg = (g == 2) ? 2.8853900817779268f : -1.4426950408889634f;
    P2[idx] = acc * sg;
}

// ---------------------------------------------------------------------------
// Kernel 2: r4 champion structure (197us steady) + packed-FP32 gate algebra.
// Issue model (calibrated on r3: trans = 16 cyc/wave-op): per-SIMD issue
// ~405 cyc of the ~800-cyc step; stalls are exchange latency (~215) +
// chain latency. Conservation: per-SIMD trans work is invariant under any
// wave/block rearrangement at 16 batches/CU, and co-locating independent
// recurrences halves active CUs (exact wash) -> only lever is issue count.
// Packed algebra done with plain ext-vector +/* operators (v_pk_mul/add);
// the three fma sites are scalar fmaf pairs (bitwise-identical per
// component; avoids __builtin_elementwise_fma as an infra-failure hedge).
// ---------------------------------------------------------------------------
__global__ __launch_bounds__(256)
__attribute__((amdgpu_waves_per_eu(1, 1)))
void lstm_head_kernel(const int* __restrict__ ids,
                      const float* __restrict__ P2,   // [1000][32][4], pre-scaled
                      const float* __restrict__ R,    // rec_kernel [32][128]
                      const float* __restrict__ w1,   // [32][32]
                      const float* __restrict__ b1,   // [32]
                      const float* __restrict__ w2,   // [32]
                      const float* __restrict__ b2,   // [1]
                      float* __restrict__ out) {
    // per col row: hi dwords [0..15] | lo dwords [16..31] | pad [4]
    __shared__ __align__(16) uint32_t hbuf[2][16][36];
    __shared__ float hfin[16][33];

    const int tid  = threadIdx.x;
    const int w    = tid >> 6;        // wave 0..3
    const int lane = tid & 63;
    const int col  = lane & 15;       // batch within group
    const int quad = lane >> 4;       // 0..3
    const int bb   = blockIdx.x * 16;
    const int u0   = 8 * w + 2 * quad;   // adjacent unit pair
    const int u1   = u0 + 1;

    const float PL2E   =  2.8853900817779268f;   // 2*log2(e)
    const float NL2E   = -1.4426950408889634f;
    const float N2PL2E = -5.7707801635558536f;   // -2*PL2E

    // ---- A fragments (identity k-order: short s=2r+e <-> k=8*quad+s) ----
    union V8 { uint32_t u[4]; v8s v; };
    V8 A0hi, A0lo, A1hi, A1lo;
    {
        int tt = col >> 2, g = col & 3;
        float sg = (g == 2) ? PL2E : NL2E;
        int gc0 = g * 32 + 8 * w + 2 * tt;
        int gc1 = gc0 + 1;
#pragma unroll
        for (int r = 0; r < 4; ++r) {
            uint32_t h0p[2], l0p[2], h1p[2], l1p[2];
#pragma unroll
            for (int e = 0; e < 2; ++e) {
                int k = quad * 8 + 2 * r + e;
                float x0 = R[k * G4 + gc0] * sg;
                uint32_t hb0 = bf16rne(x0);
                h0p[e] = hb0;
                l0p[e] = bf16rne(x0 - __uint_as_float(hb0 << 16));
                float x1 = R[k * G4 + gc1] * sg;
                uint32_t hb1 = bf16rne(x1);
                h1p[e] = hb1;
                l1p[e] = bf16rne(x1 - __uint_as_float(hb1 << 16));
            }
            A0hi.u[r] = h0p[0] | (h0p[1] << 16);
            A0lo.u[r] = l0p[0] | (l0p[1] << 16);
            A1hi.u[r] = h1p[0] | (h1p[1] << 16);
            A1lo.u[r] = l1p[0] | (l1p[1] << 16);
        }
    }

    for (int i = tid; i < 2 * 16 * 36; i += 256)
        ((uint32_t*)hbuf)[i] = 0u;

    // ---- loop-invariant LDS addresses (conflict-free by analysis) ----
    const uint32_t* rd[2] = { &hbuf[0][col][4 * quad],
                              &hbuf[1][col][4 * quad] };      // Bhi; Blo at +16
    uint32_t* wr[2] = { &hbuf[1][col][4 * w + quad],
                        &hbuf[0][col][4 * w + quad] };        // hi; lo at +16

    // ---- xz prefetch: contiguous 32B (units u0,u1 x 4 gates), dist-2,
    //      ping-pong E/O banks, zero moves ----
    const int* __restrict__ idrow = ids + (size_t)(bb + col) * TSTEPS;
    const float* __restrict__ baseL = P2 + 4 * u0;   // + id*G4 per step
    v4f xzE0, xzE1, xzO0, xzO1;
    {
        const float* p0 = baseL + (size_t)idrow[0] * G4;
        const float* p1 = baseL + (size_t)idrow[1] * G4;
        xzE0 = *(const v4f*)(p0);
        xzE1 = *(const v4f*)(p0 + 4);
        xzO0 = *(const v4f*)(p1);
        xzO1 = *(const v4f*)(p1 + 4);
    }
    int idE = idrow[2];
    int idO = idrow[3];

    v2f cc = {0.f, 0.f};
    v2f hv2 = {0.f, 0.f};
    const v4f vzero = {0.f, 0.f, 0.f, 0.f};

    __syncthreads();

    union V8R { uint4 q; v8s v; };

#define STEP(PB, XZ0, XZ1, IDX, T)                                              \
    {                                                                           \
        /* B fragments: direct b128 reads ARE Bhi/Blo (identity k-order) */     \
        V8R Bhi, Blo;                                                           \
        Bhi.q = *(const uint4*)(rd[PB]);                                        \
        Blo.q = *(const uint4*)(rd[PB] + 16);                                   \
        v4f ma0 = __builtin_amdgcn_mfma_f32_16x16x32_bf16(A0lo.v, Bhi.v, vzero, 0, 0, 0); \
        v4f mb0 = __builtin_amdgcn_mfma_f32_16x16x32_bf16(A0hi.v, Blo.v, vzero, 0, 0, 0); \
        v4f mc0 = __builtin_amdgcn_mfma_f32_16x16x32_bf16(A0hi.v, Bhi.v, XZ0, 0, 0, 0);   \
        v4f ma1 = __builtin_amdgcn_mfma_f32_16x16x32_bf16(A1lo.v, Bhi.v, vzero, 0, 0, 0); \
        v4f mb1 = __builtin_amdgcn_mfma_f32_16x16x32_bf16(A1hi.v, Blo.v, vzero, 0, 0, 0); \
        v4f mc1 = __builtin_amdgcn_mfma_f32_16x16x32_bf16(A1hi.v, Bhi.v, XZ1, 0, 0, 0);   \
        /* xz banks consumed above -> refill same bank for t+2 (no moves) */    \
        {                                                                       \
            const float* pf_ = baseL + (size_t)(IDX) * G4;                      \
            XZ0 = *(const v4f*)(pf_);                                           \
            XZ1 = *(const v4f*)(pf_ + 4);                                       \
        }                                                                       \
        { int nt_ = (T) + 4; IDX = idrow[nt_ < TSTEPS ? nt_ : (TSTEPS - 1)]; }  \
        v4f z0 = (ma0 + mb0) + mc0;                                             \
        v4f z1 = (ma1 + mb1) + mc1;                                             \
        /* grouped-reciprocal gates, packed across the (u0,u1) pair.           \
           Component math bitwise-identical to the scalar r4 version. */        \
        float ei0 = fexp2(z0[0]), ei1 = fexp2(z1[0]);                           \
        float ef0 = fexp2(z0[1]), ef1 = fexp2(z1[1]);                           \
        float eg0 = fexp2(z0[2]), eg1 = fexp2(z1[2]);                           \
        float eq0 = fexp2(z0[3]), eq1 = fexp2(z1[3]);                           \
        v2f di = v2f{ei0, ei1} + 1.f;                                           \
        v2f df = v2f{ef0, ef1} + 1.f;                                           \
        v2f dc = v2f{eg0, eg1} + 1.f;                                           \
        v2f dq = v2f{eq0, eq1} + 1.f;                                           \
        v2f Pp = di * df, Qq = dc * dq;                                         \
        v2f PQ = Pp * Qq;                                                       \
        v2f rr; rr.x = frcp(PQ.x); rr.y = frcp(PQ.y);                           \
        v2f rP = rr * Qq, rQ = rr * Pp;                                         \
        v2f ig = rP * df, fg = rP * di, rc = rQ * dq, og = rQ * dc;             \
        v2f tz; tz.x = fmaf(N2PL2E, rc.x, PL2E);                                \
                tz.y = fmaf(N2PL2E, rc.y, PL2E);                                \
        v2f itz = ig * tz;                                                      \
        cc.x = fmaf(fg.x, cc.x, itz.x);                                         \
        cc.y = fmaf(fg.y, cc.y, itz.y);                                         \
        float ecc0 = fexp2(cc.x), ecc1 = fexp2(cc.y);                           \
        v2f dn = v2f{ecc0, ecc1} + 1.f;                                         \
        v2f tc; tc.x = fmaf(-2.f, frcp(dn.x), 1.f);                             \
                tc.y = fmaf(-2.f, frcp(dn.y), 1.f);                             \
        hv2 = og * tc;                                                          \
        /* split-bf16 pack: one hi dword {u0,u1}, one lo dword */               \
        uint32_t ph = cvtpk_bf16(hv2.x, hv2.y);                                 \
        wr[PB][0] = ph;                                                         \
        float lo0 = hv2.x - __uint_as_float(ph << 16);                          \
        float lo1 = hv2.y - __uint_as_float(ph & 0xffff0000u);                  \
        wr[PB][16] = cvtpk_bf16(lo0, lo1);                                      \
        /* raw barrier: LDS drain only (xz loads live across it) */             \
        asm volatile("s_waitcnt lgkmcnt(0)\n\ts_barrier" ::: "memory");         \
    }

    for (int t = 0; t < TSTEPS; t += 2) {
        STEP(0, xzE0, xzE1, idE, t)
        STEP(1, xzO0, xzO1, idO, t + 1)
    }
#undef STEP

    // ---- MLP head ----
    hfin[col][u0] = hv2.x;
    hfin[col][u1] = hv2.y;
    __syncthreads();

    int u = tid & 31;
    for (int bq = tid >> 5; bq < 16; bq += 8) {
        float y = b1[u];
#pragma unroll
        for (int k = 0; k < HDIM; ++k)
            y = fmaf(hfin[bq][k], w1[k * HDIM + u], y);
        y = fmaxf(y, 0.f);
        float vv = y * w2[u];
#pragma unroll
        for (int off = 16; off >= 1; off >>= 1)
            vv += __shfl_xor(vv, off);
        if (u == 0) out[bb + bq] = vv + b2[0];
    }
}

extern "C" void kernel_launch(void* const* d_in, const int* in_sizes, int n_in,
                              void* d_out, int out_size, void* d_ws, size_t ws_size,
                              hipStream_t stream) {
    const int*   ids  = (const int*)d_in[0];
    const float* emb  = (const float*)d_in[1];
    const float* kern = (const float*)d_in[2];
    const float* rec  = (const float*)d_in[3];
    const float* w1   = (const float*)d_in[4];
    const float* b1   = (const float*)d_in[5];
    const float* w2   = (const float*)d_in[6];
    const float* b2   = (const float*)d_in[7];
    float* out = (float*)d_out;
    float* P2  = (float*)d_ws;   // 512 KB scratch

    precompute_P2_kernel<<<(HASH_BUCKETS * G4 + 255) / 256, 256, 0, stream>>>(
        emb, kern, P2);
    lstm_head_kernel<<<BATCH / 16, 256, 0, stream>>>(
        ids, P2, rec, w1, b1, w2, b2, out);
}

// Round 8
// 243.131 us; speedup vs baseline: 1.0003x; 1.0003x over previous
//
#include <hip/hip_runtime.h>
#include <stdint.h>

#define HASH_BUCKETS 1000
#define EMB_DIM 16
#define HDIM 32
#define G4 128   // 4*HDIM
#define TSTEPS 512
#define BATCH 4096

typedef short v8s __attribute__((ext_vector_type(8)));   // 8 bf16 (4 VGPRs)
typedef float v4f __attribute__((ext_vector_type(4)));   // MFMA acc
typedef float v2f __attribute__((ext_vector_type(2)));   // packed f32 pair

__device__ __forceinline__ float frcp(float x) {
    float r; asm("v_rcp_f32 %0, %1" : "=v"(r) : "v"(x)); return r;
}
__device__ __forceinline__ float fexp2(float x) {
    float r; asm("v_exp_f32 %0, %1" : "=v"(r) : "v"(x)); return r;
}
// packed f32->bf16 (RNE): dst.lo16 = bf16(a), dst.hi16 = bf16(b)
__device__ __forceinline__ uint32_t cvtpk_bf16(float a, float b) {
    uint32_t r; asm("v_cvt_pk_bf16_f32 %0, %1, %2" : "=v"(r) : "v"(a), "v"(b)); return r;
}
// f32 -> bf16 (RNE), bits in low 16 (A-build only, once per launch)
__device__ __forceinline__ uint32_t bf16rne(float x) {
    uint32_t u = __float_as_uint(x);
    return (u + 0x7FFFu + ((u >> 16) & 1u)) >> 16;
}

// ---------------------------------------------------------------------------
// Kernel 1 (unchanged): embedding folded through input projection, gate
// exp2-scaling folded in: i/f/o rows x (-log2 e), c-row x (+2 log2 e).
// P2[bucket][h][g] = s_g * sum_e emb[bucket][e] * kernel[e][g*32 + h]
// ---------------------------------------------------------------------------
__global__ void precompute_P2_kernel(const float* __restrict__ emb,
                                     const float* __restrict__ kern,
                                     float* __restrict__ P2) {
    int idx = blockIdx.x * blockDim.x + threadIdx.x;
    if (idx >= HASH_BUCKETS * G4) return;
    int row = idx >> 7;
    int c2  = idx & 127;
    int h = c2 >> 2;
    int g = c2 & 3;
    float acc = 0.f;
#pragma unroll
    for (int e = 0; e < EMB_DIM; ++e)
        acc = fmaf(emb[row * EMB_DIM + e], kern[e * G4 + g * 32 + h], acc);
    float sg = (g == 2) ? 2.8853900817779268f : -1.4426950408889634f;
    P2[idx] = acc * sg;
}

// ---------------------------------------------------------------------------
// Kernel 2: r7 champion structure, CHAIN-SHORTENED this round.
// Evidence: wall = 512 x single-wave chain (r1=r2; r3 regression; 2blk/CU
// conservation). VALUBusy 44.6% at ~790cyc/step -> ~435cyc exposed latency.
// Changes:
//  (a) DROP the h-lo exchange path: h crosses the barrier as plain bf16
//      (RNE). A stays split (Ahi+Alo), so R-quantization is still
//      compensated; only h-quantization (zero-mean, ~2^-9 rel) is added.
//      Removes per step: 2 MFMAs, 1 ds_read_b128, 1 ds_write, 1 cvt_pk+sub
//      on the pre-barrier chain, 1 z-add level, shorter lgkm drain.
//      DELIBERATE precision trade: absmax est 1.5e-5 -> ~1e-4.
//  (b) grouped rcp across the (u0,u1) pair for BOTH the gate product and
//      the tanh(c) denominator: 4 trans -> 2 trans (+6 cheap muls).
//  (c) hv = fma(-2*og, rn, og) with -2*og computed off-chain: -1 level.
// Everything else identical to the 195us r7 run.
// ---------------------------------------------------------------------------
__global__ __launch_bounds__(256)
__attribute__((amdgpu_waves_per_eu(1, 1)))
void lstm_head_kernel(const int* __restrict__ ids,
                      const float* __restrict__ P2,   // [1000][32][4], pre-scaled
                      const float* __restrict__ R,    // rec_kernel [32][128]
                      const float* __restrict__ w1,   // [32][32]
                      const float* __restrict__ b1,   // [32]
                      const float* __restrict__ w2,   // [32]
                      const float* __restrict__ b2,   // [1]
                      float* __restrict__ out) {
    // per col row: hi dwords [0..15] | (unused legacy lo region) | pad
    __shared__ __align__(16) uint32_t hbuf[2][16][36];
    __shared__ float hfin[16][33];

    const int tid  = threadIdx.x;
    const int w    = tid >> 6;        // wave 0..3
    const int lane = tid & 63;
    const int col  = lane & 15;       // batch within group
    const int quad = lane >> 4;       // 0..3
    const int bb   = blockIdx.x * 16;
    const int u0   = 8 * w + 2 * quad;   // adjacent unit pair
    const int u1   = u0 + 1;

    const float PL2E   =  2.8853900817779268f;   // 2*log2(e)
    const float NL2E   = -1.4426950408889634f;
    const float N2PL2E = -5.7707801635558536f;   // -2*PL2E

    // ---- A fragments (identity k-order: short s=2r+e <-> k=8*quad+s) ----
    union V8 { uint32_t u[4]; v8s v; };
    V8 A0hi, A0lo, A1hi, A1lo;
    {
        int tt = col >> 2, g = col & 3;
        float sg = (g == 2) ? PL2E : NL2E;
        int gc0 = g * 32 + 8 * w + 2 * tt;
        int gc1 = gc0 + 1;
#pragma unroll
        for (int r = 0; r < 4; ++r) {
            uint32_t h0p[2], l0p[2], h1p[2], l1p[2];
#pragma unroll
            for (int e = 0; e < 2; ++e) {
                int k = quad * 8 + 2 * r + e;
                float x0 = R[k * G4 + gc0] * sg;
                uint32_t hb0 = bf16rne(x0);
                h0p[e] = hb0;
                l0p[e] = bf16rne(x0 - __uint_as_float(hb0 << 16));
                float x1 = R[k * G4 + gc1] * sg;
                uint32_t hb1 = bf16rne(x1);
                h1p[e] = hb1;
                l1p[e] = bf16rne(x1 - __uint_as_float(hb1 << 16));
            }
            A0hi.u[r] = h0p[0] | (h0p[1] << 16);
            A0lo.u[r] = l0p[0] | (l0p[1] << 16);
            A1hi.u[r] = h1p[0] | (h1p[1] << 16);
            A1lo.u[r] = l1p[0] | (l1p[1] << 16);
        }
    }

    for (int i = tid; i < 2 * 16 * 36; i += 256)
        ((uint32_t*)hbuf)[i] = 0u;

    // ---- loop-invariant LDS addresses (conflict-free by analysis) ----
    const uint32_t* rd[2] = { &hbuf[0][col][4 * quad],
                              &hbuf[1][col][4 * quad] };      // Bhi only
    uint32_t* wr[2] = { &hbuf[1][col][4 * w + quad],
                        &hbuf[0][col][4 * w + quad] };        // hi only

    // ---- xz prefetch: contiguous 32B (units u0,u1 x 4 gates), dist-2,
    //      ping-pong E/O banks, zero moves ----
    const int* __restrict__ idrow = ids + (size_t)(bb + col) * TSTEPS;
    const float* __restrict__ baseL = P2 + 4 * u0;   // + id*G4 per step
    v4f xzE0, xzE1, xzO0, xzO1;
    {
        const float* p0 = baseL + (size_t)idrow[0] * G4;
        const float* p1 = baseL + (size_t)idrow[1] * G4;
        xzE0 = *(const v4f*)(p0);
        xzE1 = *(const v4f*)(p0 + 4);
        xzO0 = *(const v4f*)(p1);
        xzO1 = *(const v4f*)(p1 + 4);
    }
    int idE = idrow[2];
    int idO = idrow[3];

    v2f cc = {0.f, 0.f};
    v2f hv2 = {0.f, 0.f};
    const v4f vzero = {0.f, 0.f, 0.f, 0.f};

    __syncthreads();

    union V8R { uint4 q; v8s v; };

#define STEP(PB, XZ0, XZ1, IDX, T)                                              \
    {                                                                           \
        /* B fragment: ONE b128 read IS Bhi (identity k-order) */               \
        V8R Bhi;                                                                \
        Bhi.q = *(const uint4*)(rd[PB]);                                        \
        v4f ma0 = __builtin_amdgcn_mfma_f32_16x16x32_bf16(A0lo.v, Bhi.v, vzero, 0, 0, 0); \
        v4f mc0 = __builtin_amdgcn_mfma_f32_16x16x32_bf16(A0hi.v, Bhi.v, XZ0, 0, 0, 0);   \
        v4f ma1 = __builtin_amdgcn_mfma_f32_16x16x32_bf16(A1lo.v, Bhi.v, vzero, 0, 0, 0); \
        v4f mc1 = __builtin_amdgcn_mfma_f32_16x16x32_bf16(A1hi.v, Bhi.v, XZ1, 0, 0, 0);   \
        /* xz banks consumed above -> refill same bank for t+2 (no moves) */    \
        {                                                                       \
            const float* pf_ = baseL + (size_t)(IDX) * G4;                      \
            XZ0 = *(const v4f*)(pf_);                                           \
            XZ1 = *(const v4f*)(pf_ + 4);                                       \
        }                                                                       \
        { int nt_ = (T) + 4; IDX = idrow[nt_ < TSTEPS ? nt_ : (TSTEPS - 1)]; }  \
        v4f z0 = ma0 + mc0;                                                     \
        v4f z1 = ma1 + mc1;                                                     \
        /* gates: z pre-scaled, exp2 direct; rcps GROUPED across unit pair */   \
        float ei0 = fexp2(z0[0]), ei1 = fexp2(z1[0]);                           \
        float ef0 = fexp2(z0[1]), ef1 = fexp2(z1[1]);                           \
        float eg0 = fexp2(z0[2]), eg1 = fexp2(z1[2]);                           \
        float eq0 = fexp2(z0[3]), eq1 = fexp2(z1[3]);                           \
        v2f di = v2f{ei0, ei1} + 1.f;                                           \
        v2f df = v2f{ef0, ef1} + 1.f;                                           \
        v2f dc = v2f{eg0, eg1} + 1.f;                                           \
        v2f dq = v2f{eq0, eq1} + 1.f;                                           \
        v2f Pp = di * df, Qq = dc * dq;                                         \
        v2f PQ = Pp * Qq;                                                       \
        float R4 = frcp(PQ.x * PQ.y);                                           \
        v2f rr; rr.x = R4 * PQ.y; rr.y = R4 * PQ.x;                             \
        v2f rP = rr * Qq, rQ = rr * Pp;                                         \
        v2f ig = rP * df, fg = rP * di, rc = rQ * dq, og = rQ * dc;             \
        v2f tz; tz.x = fmaf(N2PL2E, rc.x, PL2E);                                \
                tz.y = fmaf(N2PL2E, rc.y, PL2E);                                \
        v2f itz = ig * tz;                                                      \
        cc.x = fmaf(fg.x, cc.x, itz.x);                                         \
        cc.y = fmaf(fg.y, cc.y, itz.y);                                         \
        float ecc0 = fexp2(cc.x), ecc1 = fexp2(cc.y);                           \
        v2f dn = v2f{ecc0, ecc1} + 1.f;                                         \
        float R2 = frcp(dn.x * dn.y);                                           \
        v2f rn; rn.x = R2 * dn.y; rn.y = R2 * dn.x;                             \
        v2f m2og = og * (-2.f);   /* off-chain (og ready early) */              \
        hv2.x = fmaf(m2og.x, rn.x, og.x);                                       \
        hv2.y = fmaf(m2og.y, rn.y, og.y);                                       \
        /* publish h as plain bf16 pair: ONE cvt_pk + ONE ds_write_b32 */       \
        wr[PB][0] = cvtpk_bf16(hv2.x, hv2.y);                                   \
        /* raw barrier: LDS drain only (xz loads live across it) */             \
        asm volatile("s_waitcnt lgkmcnt(0)\n\ts_barrier" ::: "memory");         \
    }

    for (int t = 0; t < TSTEPS; t += 2) {
        STEP(0, xzE0, xzE1, idE, t)
        STEP(1, xzO0, xzO1, idO, t + 1)
    }
#undef STEP

    // ---- MLP head ----
    hfin[col][u0] = hv2.x;
    hfin[col][u1] = hv2.y;
    __syncthreads();

    int u = tid & 31;
    for (int bq = tid >> 5; bq < 16; bq += 8) {
        float y = b1[u];
#pragma unroll
        for (int k = 0; k < HDIM; ++k)
            y = fmaf(hfin[bq][k], w1[k * HDIM + u], y);
        y = fmaxf(y, 0.f);
        float vv = y * w2[u];
#pragma unroll
        for (int off = 16; off >= 1; off >>= 1)
            vv += __shfl_xor(vv, off);
        if (u == 0) out[bb + bq] = vv + b2[0];
    }
}

extern "C" void kernel_launch(void* const* d_in, const int* in_sizes, int n_in,
                              void* d_out, int out_size, void* d_ws, size_t ws_size,
                              hipStream_t stream) {
    const int*   ids  = (const int*)d_in[0];
    const float* emb  = (const float*)d_in[1];
    const float* kern = (const float*)d_in[2];
    const float* rec  = (const float*)d_in[3];
    const float* w1   = (const float*)d_in[4];
    const float* b1   = (const float*)d_in[5];
    const float* w2   = (const float*)d_in[6];
    const float* b2   = (const float*)d_in[7];
    float* out = (float*)d_out;
    float* P2  = (float*)d_ws;   // 512 KB scratch

    precompute_P2_kernel<<<(HASH_BUCKETS * G4 + 255) / 256, 256, 0, stream>>>(
        emb, kern, P2);
    lstm_head_kernel<<<BATCH / 16, 256, 0, stream>>>(
        ids, P2, rec, w1, b1, w2, b2, out);
}

// Round 9
// 242.522 us; speedup vs baseline: 1.0028x; 1.0025x over previous
//
#include <hip/hip_runtime.h>
#include <stdint.h>

#define HASH_BUCKETS 1000
#define EMB_DIM 16
#define HDIM 32
#define G4 128   // 4*HDIM
#define TSTEPS 512
#define BATCH 4096

typedef short v8s __attribute__((ext_vector_type(8)));   // 8 bf16 (4 VGPRs)
typedef float v4f __attribute__((ext_vector_type(4)));   // MFMA acc
typedef float v2f __attribute__((ext_vector_type(2)));   // packed f32 pair

__device__ __forceinline__ float frcp(float x) {
    float r; asm("v_rcp_f32 %0, %1" : "=v"(r) : "v"(x)); return r;
}
__device__ __forceinline__ float fexp2(float x) {
    float r; asm("v_exp_f32 %0, %1" : "=v"(r) : "v"(x)); return r;
}
// packed f32->bf16 (RNE): dst.lo16 = bf16(a), dst.hi16 = bf16(b)
__device__ __forceinline__ uint32_t cvtpk_bf16(float a, float b) {
    uint32_t r; asm("v_cvt_pk_bf16_f32 %0, %1, %2" : "=v"(r) : "v"(a), "v"(b)); return r;
}
// f32 -> bf16 (RNE), bits in low 16 (A-build only, once per launch)
__device__ __forceinline__ uint32_t bf16rne(float x) {
    uint32_t u = __float_as_uint(x);
    return (u + 0x7FFFu + ((u >> 16) & 1u)) >> 16;
}

// ---------------------------------------------------------------------------
// Kernel 1 (unchanged): embedding folded through input projection, gate
// exp2-scaling folded in: i/f/o rows x (-log2 e), c-row x (+2 log2 e).
// P2[bucket][h][g] = s_g * sum_e emb[bucket][e] * kernel[e][g*32 + h]
// ---------------------------------------------------------------------------
__global__ void precompute_P2_kernel(const float* __restrict__ emb,
                                     const float* __restrict__ kern,
                                     float* __restrict__ P2) {
    int idx = blockIdx.x * blockDim.x + threadIdx.x;
    if (idx >= HASH_BUCKETS * G4) return;
    int row = idx >> 7;
    int c2  = idx & 127;
    int h = c2 >> 2;
    int g = c2 & 3;
    float acc = 0.f;
#pragma unroll
    for (int e = 0; e < EMB_DIM; ++e)
        acc = fmaf(emb[row * EMB_DIM + e], kern[e * G4 + g * 32 + h], acc);
    float sg = (g == 2) ? 2.8853900817779268f : -1.4426950408889634f;
    P2[idx] = acc * sg;
}

// ---------------------------------------------------------------------------
// Kernel 2: r8 champion, chain-trimmed further:
//  (a) A-lo compensation DROPPED: R crosses into the MFMA as plain bf16-RNE.
//      Evidence: r8 dropped h-lo and absmax did not move (pinned at 2^-16 =
//      output ulp) -> zero-mean quantization noise cancels across the 32-dot
//      and decays via the forget gate; the same argument bounds R-RNE.
//      Per step this removes: 2 MFMAs (4->2), the z-add level (z = MFMA
//      output directly, xz rides the C-operand), ~8 VGPRs.
//  (b) everything else byte-identical to the 190us r8 run (single bf16 h
//      exchange, grouped rcp pairs, pk-f32 gate algebra, conflict-free LDS,
//      dist-2 ping-pong xz prefetch, raw lgkm-only barrier).
// If this lands <=5us, the 4-wave exchange structure is at its serial-
// latency floor (exchange ~150cyc + trans chain ~180cyc irreducible here).
// ---------------------------------------------------------------------------
__global__ __launch_bounds__(256)
__attribute__((amdgpu_waves_per_eu(1, 1)))
void lstm_head_kernel(const int* __restrict__ ids,
                      const float* __restrict__ P2,   // [1000][32][4], pre-scaled
                      const float* __restrict__ R,    // rec_kernel [32][128]
                      const float* __restrict__ w1,   // [32][32]
                      const float* __restrict__ b1,   // [32]
                      const float* __restrict__ w2,   // [32]
                      const float* __restrict__ b2,   // [1]
                      float* __restrict__ out) {
    // per col row: hi dwords [0..15] | (legacy lo region, unused) | pad
    __shared__ __align__(16) uint32_t hbuf[2][16][36];
    __shared__ float hfin[16][33];

    const int tid  = threadIdx.x;
    const int w    = tid >> 6;        // wave 0..3
    const int lane = tid & 63;
    const int col  = lane & 15;       // batch within group
    const int quad = lane >> 4;       // 0..3
    const int bb   = blockIdx.x * 16;
    const int u0   = 8 * w + 2 * quad;   // adjacent unit pair
    const int u1   = u0 + 1;

    const float PL2E   =  2.8853900817779268f;   // 2*log2(e)
    const float NL2E   = -1.4426950408889634f;
    const float N2PL2E = -5.7707801635558536f;   // -2*PL2E

    // ---- A fragments, plain bf16-RNE (identity k-order: s=2r+e <-> k=8q+s) ----
    union V8 { uint32_t u[4]; v8s v; };
    V8 A0, A1;
    {
        int tt = col >> 2, g = col & 3;
        float sg = (g == 2) ? PL2E : NL2E;
        int gc0 = g * 32 + 8 * w + 2 * tt;
        int gc1 = gc0 + 1;
#pragma unroll
        for (int r = 0; r < 4; ++r) {
            uint32_t h0p[2], h1p[2];
#pragma unroll
            for (int e = 0; e < 2; ++e) {
                int k = quad * 8 + 2 * r + e;
                h0p[e] = bf16rne(R[k * G4 + gc0] * sg);
                h1p[e] = bf16rne(R[k * G4 + gc1] * sg);
            }
            A0.u[r] = h0p[0] | (h0p[1] << 16);
            A1.u[r] = h1p[0] | (h1p[1] << 16);
        }
    }

    for (int i = tid; i < 2 * 16 * 36; i += 256)
        ((uint32_t*)hbuf)[i] = 0u;

    // ---- loop-invariant LDS addresses (conflict-free by analysis) ----
    const uint32_t* rd[2] = { &hbuf[0][col][4 * quad],
                              &hbuf[1][col][4 * quad] };      // Bhi
    uint32_t* wr[2] = { &hbuf[1][col][4 * w + quad],
                        &hbuf[0][col][4 * w + quad] };        // hi

    // ---- xz prefetch: contiguous 32B (units u0,u1 x 4 gates), dist-2,
    //      ping-pong E/O banks, zero moves ----
    const int* __restrict__ idrow = ids + (size_t)(bb + col) * TSTEPS;
    const float* __restrict__ baseL = P2 + 4 * u0;   // + id*G4 per step
    v4f xzE0, xzE1, xzO0, xzO1;
    {
        const float* p0 = baseL + (size_t)idrow[0] * G4;
        const float* p1 = baseL + (size_t)idrow[1] * G4;
        xzE0 = *(const v4f*)(p0);
        xzE1 = *(const v4f*)(p0 + 4);
        xzO0 = *(const v4f*)(p1);
        xzO1 = *(const v4f*)(p1 + 4);
    }
    int idE = idrow[2];
    int idO = idrow[3];

    v2f cc = {0.f, 0.f};
    v2f hv2 = {0.f, 0.f};

    __syncthreads();

    union V8R { uint4 q; v8s v; };

#define STEP(PB, XZ0, XZ1, IDX, T)                                              \
    {                                                                           \
        /* B fragment: ONE b128 read IS Bhi (identity k-order) */               \
        V8R Bhi;                                                                \
        Bhi.q = *(const uint4*)(rd[PB]);                                        \
        /* z = R^T h + xz in ONE MFMA per unit (xz rides the C operand) */      \
        v4f z0 = __builtin_amdgcn_mfma_f32_16x16x32_bf16(A0.v, Bhi.v, XZ0, 0, 0, 0); \
        v4f z1 = __builtin_amdgcn_mfma_f32_16x16x32_bf16(A1.v, Bhi.v, XZ1, 0, 0, 0); \
        /* xz banks consumed above -> refill same bank for t+2 (no moves) */    \
        {                                                                       \
            const float* pf_ = baseL + (size_t)(IDX) * G4;                      \
            XZ0 = *(const v4f*)(pf_);                                           \
            XZ1 = *(const v4f*)(pf_ + 4);                                       \
        }                                                                       \
        { int nt_ = (T) + 4; IDX = idrow[nt_ < TSTEPS ? nt_ : (TSTEPS - 1)]; }  \
        /* gates: z pre-scaled, exp2 direct; rcps GROUPED across unit pair */   \
        float ei0 = fexp2(z0[0]), ei1 = fexp2(z1[0]);                           \
        float ef0 = fexp2(z0[1]), ef1 = fexp2(z1[1]);                           \
        float eg0 = fexp2(z0[2]), eg1 = fexp2(z1[2]);                           \
        float eq0 = fexp2(z0[3]), eq1 = fexp2(z1[3]);                           \
        v2f di = v2f{ei0, ei1} + 1.f;                                           \
        v2f df = v2f{ef0, ef1} + 1.f;                                           \
        v2f dc = v2f{eg0, eg1} + 1.f;                                           \
        v2f dq = v2f{eq0, eq1} + 1.f;                                           \
        v2f Pp = di * df, Qq = dc * dq;                                         \
        v2f PQ = Pp * Qq;                                                       \
        float R4 = frcp(PQ.x * PQ.y);                                           \
        v2f rr; rr.x = R4 * PQ.y; rr.y = R4 * PQ.x;                             \
        v2f rP = rr * Qq, rQ = rr * Pp;                                         \
        v2f ig = rP * df, fg = rP * di, rc = rQ * dq, og = rQ * dc;             \
        v2f tz; tz.x = fmaf(N2PL2E, rc.x, PL2E);                                \
                tz.y = fmaf(N2PL2E, rc.y, PL2E);                                \
        v2f itz = ig * tz;                                                      \
        cc.x = fmaf(fg.x, cc.x, itz.x);                                         \
        cc.y = fmaf(fg.y, cc.y, itz.y);                                         \
        float ecc0 = fexp2(cc.x), ecc1 = fexp2(cc.y);                           \
        v2f dn = v2f{ecc0, ecc1} + 1.f;                                         \
        float R2 = frcp(dn.x * dn.y);                                           \
        v2f rn; rn.x = R2 * dn.y; rn.y = R2 * dn.x;                             \
        v2f m2og = og * (-2.f);   /* off-chain (og ready early) */              \
        hv2.x = fmaf(m2og.x, rn.x, og.x);                                       \
        hv2.y = fmaf(m2og.y, rn.y, og.y);                                       \
        /* publish h as plain bf16 pair: ONE cvt_pk + ONE ds_write_b32 */       \
        wr[PB][0] = cvtpk_bf16(hv2.x, hv2.y);                                   \
        /* raw barrier: LDS drain only (xz loads live across it) */             \
        asm volatile("s_waitcnt lgkmcnt(0)\n\ts_barrier" ::: "memory");         \
    }

    for (int t = 0; t < TSTEPS; t += 2) {
        STEP(0, xzE0, xzE1, idE, t)
        STEP(1, xzO0, xzO1, idO, t + 1)
    }
#undef STEP

    // ---- MLP head ----
    hfin[col][u0] = hv2.x;
    hfin[col][u1] = hv2.y;
    __syncthreads();

    int u = tid & 31;
    for (int bq = tid >> 5; bq < 16; bq += 8) {
        float y = b1[u];
#pragma unroll
        for (int k = 0; k < HDIM; ++k)
            y = fmaf(hfin[bq][k], w1[k * HDIM + u], y);
        y = fmaxf(y, 0.f);
        float vv = y * w2[u];
#pragma unroll
        for (int off = 16; off >= 1; off >>= 1)
            vv += __shfl_xor(vv, off);
        if (u == 0) out[bb + bq] = vv + b2[0];
    }
}

extern "C" void kernel_launch(void* const* d_in, const int* in_sizes, int n_in,
                              void* d_out, int out_size, void* d_ws, size_t ws_size,
                              hipStream_t stream) {
    const int*   ids  = (const int*)d_in[0];
    const float* emb  = (const float*)d_in[1];
    const float* kern = (const float*)d_in[2];
    const float* rec  = (const float*)d_in[3];
    const float* w1   = (const float*)d_in[4];
    const float* b1   = (const float*)d_in[5];
    const float* w2   = (const float*)d_in[6];
    const float* b2   = (const float*)d_in[7];
    float* out = (float*)d_out;
    float* P2  = (float*)d_ws;   // 512 KB scratch

    precompute_P2_kernel<<<(HASH_BUCKETS * G4 + 255) / 256, 256, 0, stream>>>(
        emb, kern, P2);
    lstm_head_kernel<<<BATCH / 16, 256, 0, stream>>>(
        ids, P2, rec, w1, b1, w2, b2, out);
}